// Round 1
// baseline (670.758 us; speedup 1.0000x reference)
//
#include <hip/hip_runtime.h>
#include <hip/hip_bf16.h>

// Sizes
#define HXN 10
#define HZN 10
#define BN  256
#define AN  20
#define WUN 128
#define NTILES 6400   // (HXN*HZN) * (BN/4)
#define MROWS 80      // 4 b's * 20 a's per tile

typedef float  f32x4  __attribute__((ext_vector_type(4)));
typedef __bf16 bf16x8 __attribute__((ext_vector_type(8)));
typedef unsigned short us8 __attribute__((ext_vector_type(8)));

__device__ __forceinline__ unsigned short f2bf(float f) {
  unsigned u = __builtin_bit_cast(unsigned, f);
  u += 0x7fffu + ((u >> 16) & 1u);
  return (unsigned short)(u >> 16);
}
__device__ __forceinline__ float bf2f(unsigned short b) {
  return __builtin_bit_cast(float, ((unsigned)b) << 16);
}
__device__ __forceinline__ float elu(float x) {
  return x > 0.f ? x : (__expf(x) - 1.f);
}

// ---------------- zh nets + Pz = zh @ Wu0[104:168] ----------------
// grid: HZN*BN blocks, 64 threads
__global__ void k_zh(const float* __restrict__ Z, const float* __restrict__ Wz0,
                     const float* __restrict__ WzR, const float* __restrict__ bz,
                     const float* __restrict__ Wu0, float* __restrict__ Pz)
{
  __shared__ float cur[2][64];
  const int hz = blockIdx.x >> 8;       // /256
  const int b  = blockIdx.x & 255;
  const int j  = threadIdx.x;
  cur[0][j] = Z[b * 64 + j];
  __syncthreads();
  {
    float acc = bz[hz * 64 + j];
    for (int i = 0; i < 64; ++i) acc += cur[0][i] * Wz0[hz * 4096 + i * 64 + j];
    cur[1][j] = elu(acc);
  }
  __syncthreads();
  for (int m = 1; m < 5; ++m) {
    // layer m output buffer: m=1 -> cur[0], m=2 -> cur[1], ... = cur[(m+1)&1]
    const int s = m & 1, d = s ^ 1;
    float acc = bz[m * (HZN * 64) + hz * 64 + j];
    const float* W = WzR + ((m - 1) * HZN + hz) * 4096;
    for (int i = 0; i < 64; ++i) acc += cur[s][i] * W[i * 64 + j];
    __syncthreads();
    cur[d][j] = elu(acc);
    __syncthreads();
  }
  // final zh is in cur[1]  (m=4: d = 1)
  for (int t = 0; t < 2; ++t) {
    const int col = j + t * 64;
    float s2 = 0.f;
    for (int i = 0; i < 64; ++i) s2 += cur[1][i] * Wu0[(104 + i) * 128 + col];
    Pz[(hz * BN + b) * 128 + col] = s2;
  }
}

// ---------------- Xh nets ----------------
// grid: HXN * 1280 blocks (4 rows per block), 256 threads (wave g = row g)
__global__ __launch_bounds__(256) void k_xh(const float* __restrict__ X,
                     const float* __restrict__ Wx0, const float* __restrict__ WxR,
                     const float* __restrict__ bx, float* __restrict__ Xh)
{
  __shared__ float WL[4096];
  __shared__ float xin[4][40];
  __shared__ float cur[2][4][64];
  const int hx = blockIdx.x / 1280;
  const int rt = blockIdx.x % 1280;
  const int g = threadIdx.x >> 6;
  const int j = threadIdx.x & 63;
  const int r = rt * 4 + g;           // row within hx: r = b*20 + a, 0..5119
  if (j < 40) xin[g][j] = X[r * 40 + j];
  for (int idx = threadIdx.x; idx < 2560; idx += 256) WL[idx] = Wx0[hx * 2560 + idx];
  __syncthreads();
  {
    float acc = bx[hx * 64 + j];
    for (int i = 0; i < 40; ++i) acc += xin[g][i] * WL[i * 64 + j];
    cur[0][g][j] = elu(acc);
  }
  __syncthreads();
  for (int m = 1; m < 5; ++m) {
    for (int idx = threadIdx.x; idx < 4096; idx += 256)
      WL[idx] = WxR[((m - 1) * HXN + hx) * 4096 + idx];
    __syncthreads();
    float acc = bx[m * (HXN * 64) + hx * 64 + j];
    for (int i = 0; i < 64; ++i) acc += cur[(m - 1) & 1][g][i] * WL[i * 64 + j];
    cur[m & 1][g][j] = elu(acc);
    __syncthreads();
  }
  Xh[hx * 327680 + r * 64 + j] = cur[0][g][j];   // layer 4 -> cur[0]
}

// ---------------- R = X@Wu0[0:40] + Z@Wu0[168:232] + bu0 ----------------
// grid: 5120 blocks, 128 threads
__global__ void k_r(const float* __restrict__ X, const float* __restrict__ Z,
                    const float* __restrict__ Wu0, const float* __restrict__ bu,
                    float* __restrict__ R)
{
  __shared__ float xin[40];
  __shared__ float zin[64];
  const int row = blockIdx.x;          // b*20 + a
  const int b = row / 20;
  const int t = threadIdx.x;
  if (t < 40) xin[t] = X[row * 40 + t];
  if (t >= 64) zin[t - 64] = Z[b * 64 + (t - 64)];
  __syncthreads();
  float acc = bu[t];
  for (int i = 0; i < 40; ++i) acc += xin[i] * Wu0[i * 128 + t];
  for (int i = 0; i < 64; ++i) acc += zin[i] * Wu0[(168 + i) * 128 + t];
  R[row * 128 + t] = acc;
}

// ---------------- Q = R + Xh@Wu0[40:104] ----------------
// grid: HXN*5120 blocks, 128 threads
__global__ void k_q(const float* __restrict__ Xh, const float* __restrict__ R,
                    const float* __restrict__ Wu0, float* __restrict__ Q)
{
  __shared__ float xh[64];
  const int gid = blockIdx.x;
  const int hx = gid / 5120, r = gid % 5120;
  const int t = threadIdx.x;
  if (t < 64) xh[t] = Xh[hx * 327680 + r * 64 + t];
  __syncthreads();
  float acc = R[r * 128 + t];
  for (int i = 0; i < 64; ++i) acc += xh[i] * Wu0[(40 + i) * 128 + t];
  Q[(size_t)hx * 655360 + r * 128 + t] = acc;
}

// ---------------- fused 4x[128x128] MLP + logits + softmax ----------------
// block: 256 threads (4 waves). Tile: one (hx,hz), 4 b's, 80 rows.
// Wave w owns n-tiles {2w, 2w+1} (32 cols) for all layers; weights in regs.
__global__ __launch_bounds__(256, 2) void k_fused(
    const float* __restrict__ Q, const float* __restrict__ Pz,
    const float* __restrict__ WuR, const float* __restrict__ bu,
    const float* __restrict__ Wlast, float* __restrict__ partial)
{
  __shared__ __align__(16) unsigned short act[2][MROWS * WUN];
  __shared__ float logits[MROWS];
  __shared__ float ebuf[MROWS];
  __shared__ float red[8];
  __shared__ float wl[WUN];

  const int tid  = threadIdx.x;
  const int wid  = tid >> 6;
  const int lane = tid & 63;
  const int l16  = lane & 15;
  const int lg   = lane >> 4;          // 0..3

  if (tid < WUN) wl[tid] = Wlast[tid];

  // Load per-wave weight B-fragments (bf16) for all 4 hidden layers.
  bf16x8 wfrag[4][4][2];
  #pragma unroll
  for (int l = 0; l < 4; ++l) {
    #pragma unroll
    for (int kk = 0; kk < 4; ++kk) {
      #pragma unroll
      for (int j = 0; j < 2; ++j) {
        const int n = (2 * wid + j) * 16 + l16;
        us8 w;
        #pragma unroll
        for (int e = 0; e < 8; ++e) {
          const int k = kk * 32 + ((e < 4) ? (4 * lg + e) : (16 + 4 * lg + (e - 4)));
          w[e] = f2bf(WuR[l * 16384 + k * 128 + n]);
        }
        wfrag[l][kk][j] = __builtin_bit_cast(bf16x8, w);
      }
    }
  }

  for (int tile = blockIdx.x; tile < NTILES; tile += gridDim.x) {
    const int H  = tile >> 6;          // 0..99
    const int tb = tile & 63;          // b-tile (4 b's)
    const int hx = H / HZN, hz = H % HZN;
    const float* qp  = Q  + (size_t)hx * 655360 + (size_t)tb * 80 * 128;
    const float* pzp = Pz + (hz * BN + tb * 4) * 128;

    // stage u1 = elu(Q + Pz) into act[0] (swizzled bf16)
    for (int idx = tid; idx < MROWS * WUN; idx += 256) {
      const int row = idx >> 7, col = idx & 127;
      float v = qp[idx] + pzp[(row / 20) * 128 + col];
      act[0][(row * 128 + col) ^ ((row & 7) << 3)] = f2bf(elu(v));
    }
    __syncthreads();

    #pragma unroll
    for (int l = 0; l < 4; ++l) {
      const int src = l & 1, dst = src ^ 1;
      f32x4 acc[5][2];
      #pragma unroll
      for (int mt = 0; mt < 5; ++mt)
        #pragma unroll
        for (int j = 0; j < 2; ++j)
          #pragma unroll
          for (int rr = 0; rr < 4; ++rr)
            acc[mt][j][rr] = 0.f;
      #pragma unroll
      for (int kk = 0; kk < 4; ++kk) {
        bf16x8 af[5];
        #pragma unroll
        for (int mt = 0; mt < 5; ++mt) {
          const int rowm = mt * 16 + l16;
          const int base = rowm * 128 + kk * 32 + 4 * lg;
          const int sw = (rowm & 7) << 3;
          const ushort4 lo = *reinterpret_cast<const ushort4*>(&act[src][base ^ sw]);
          const ushort4 hi = *reinterpret_cast<const ushort4*>(&act[src][(base + 16) ^ sw]);
          us8 a8;
          a8[0] = lo.x; a8[1] = lo.y; a8[2] = lo.z; a8[3] = lo.w;
          a8[4] = hi.x; a8[5] = hi.y; a8[6] = hi.z; a8[7] = hi.w;
          af[mt] = __builtin_bit_cast(bf16x8, a8);
        }
        #pragma unroll
        for (int mt = 0; mt < 5; ++mt)
          #pragma unroll
          for (int j = 0; j < 2; ++j)
            acc[mt][j] = __builtin_amdgcn_mfma_f32_16x16x32_bf16(
                af[mt], wfrag[l][kk][j], acc[mt][j], 0, 0, 0);
      }
      // bias + elu + store to dst
      #pragma unroll
      for (int j = 0; j < 2; ++j) {
        const int col = (2 * wid + j) * 16 + l16;
        const float bv = bu[(l + 1) * 128 + col];
        #pragma unroll
        for (int mt = 0; mt < 5; ++mt) {
          #pragma unroll
          for (int rr = 0; rr < 4; ++rr) {
            const int row = mt * 16 + 4 * lg + rr;
            act[dst][(row * 128 + col) ^ ((row & 7) << 3)] = f2bf(elu(acc[mt][j][rr] + bv));
          }
        }
      }
      __syncthreads();
    }

    // logits from act[0] (layer-4 output)
    if (tid < 160) {
      const int row = tid >> 1, half = tid & 1;
      float s = 0.f;
      for (int c = 0; c < 64; ++c) {
        const int col = half * 64 + c;
        s += bf2f(act[0][(row * 128 + col) ^ ((row & 7) << 3)]) * wl[col];
      }
      s += __shfl_xor(s, 1);
      if (half == 0) logits[row] = s;
    }
    __syncthreads();
    // softmax per group of 20 rows
    if (tid < 4) {
      float mx = -1e30f;
      for (int a = 0; a < 20; ++a) mx = fmaxf(mx, logits[tid * 20 + a]);
      red[tid] = mx;
    }
    __syncthreads();
    if (tid < MROWS) ebuf[tid] = __expf(logits[tid] - red[tid / 20]);
    __syncthreads();
    if (tid < 4) {
      float sm = 0.f;
      for (int a = 0; a < 20; ++a) sm += ebuf[tid * 20 + a];
      red[4 + tid] = 1.f / sm;
    }
    __syncthreads();
    if (tid < MROWS) {
      float p = ebuf[tid] * red[4 + tid / 20];
      p = (1e-6f + p) / (1.f + 1e-6f * 20.f);
      partial[(size_t)H * 5120 + tb * 80 + tid] = p;
    }
    __syncthreads();  // protect LDS before next tile's staging
  }
}

// ---------------- mean over the 100 (hx,hz) samples ----------------
__global__ void k_reduce(const float* __restrict__ partial, float* __restrict__ out)
{
  const int i = blockIdx.x * 256 + threadIdx.x;
  if (i < 5120) {
    float s = 0.f;
    for (int h = 0; h < 100; ++h) s += partial[(size_t)h * 5120 + i];
    out[i] = s * 0.01f;
  }
}

extern "C" void kernel_launch(void* const* d_in, const int* in_sizes, int n_in,
                              void* d_out, int out_size, void* d_ws, size_t ws_size,
                              hipStream_t stream)
{
  const float* X     = (const float*)d_in[0];
  const float* Z     = (const float*)d_in[1];
  const float* Wx0   = (const float*)d_in[2];
  const float* WxR   = (const float*)d_in[3];
  const float* bx    = (const float*)d_in[4];
  const float* Wz0   = (const float*)d_in[5];
  const float* WzR   = (const float*)d_in[6];
  const float* bz    = (const float*)d_in[7];
  const float* Wu0   = (const float*)d_in[8];
  const float* WuR   = (const float*)d_in[9];
  const float* bu    = (const float*)d_in[10];
  const float* Wlast = (const float*)d_in[11];
  float* out = (float*)d_out;

  float* ws      = (float*)d_ws;
  float* Pz      = ws;                   // 10*256*128      = 327,680
  float* Xh      = Pz + 327680;          // 10*5120*64      = 3,276,800
  float* Rb      = Xh + 3276800;         // 5120*128        = 655,360
  float* Qb      = Rb + 655360;          // 10*5120*128     = 6,553,600
  float* partial = Qb + 6553600;         // 100*5120        = 512,000

  hipLaunchKernelGGL(k_zh, dim3(HZN * BN), dim3(64), 0, stream, Z, Wz0, WzR, bz, Wu0, Pz);
  hipLaunchKernelGGL(k_xh, dim3(HXN * 1280), dim3(256), 0, stream, X, Wx0, WxR, bx, Xh);
  hipLaunchKernelGGL(k_r, dim3(5120), dim3(128), 0, stream, X, Z, Wu0, bu, Rb);
  hipLaunchKernelGGL(k_q, dim3(HXN * 5120), dim3(128), 0, stream, Xh, Rb, Wu0, Qb);
  hipLaunchKernelGGL(k_fused, dim3(512), dim3(256), 0, stream, Qb, Pz, WuR, bu, Wlast, partial);
  hipLaunchKernelGGL(k_reduce, dim3(20), dim3(256), 0, stream, partial, out);
}

// Round 5
// 397.933 us; speedup vs baseline: 1.6856x; 1.6856x over previous
//
#include <hip/hip_runtime.h>
#include <hip/hip_bf16.h>

// Sizes
#define HXN 10
#define HZN 10
#define BN  256
#define AN  20
#define WUN 128
#define NTILES 6400   // (HXN*HZN) * (BN/4)
#define MROWS 80      // 4 b's * 20 a's per tile

typedef float  f32x4  __attribute__((ext_vector_type(4)));
typedef __bf16 bf16x8 __attribute__((ext_vector_type(8)));
typedef unsigned short us8 __attribute__((ext_vector_type(8)));

__device__ __forceinline__ unsigned short f2bf(float f) {
  unsigned u = __builtin_bit_cast(unsigned, f);
  u += 0x7fffu + ((u >> 16) & 1u);   // round-to-nearest-even
  return (unsigned short)(u >> 16);
}
__device__ __forceinline__ float elu(float x) {
  return x > 0.f ? x : (__expf(x) - 1.f);
}
// column permutation so a lane's 8 fragment elements are contiguous:
// col = kk*32 + kappa(lg,e), kappa = (e<4)? 4lg+e : 16+4lg+(e-4)
// perm(col) = kk*32 + lg*8 + e
__device__ __forceinline__ int permc(int c) {
  return (c >> 5) * 32 + ((c >> 2) & 3) * 8 + ((c >> 4) & 1) * 4 + (c & 3);
}

// ---------------- zh nets + Pz = zh @ Wu0[104:168] (perm cols) ----------------
__global__ void k_zh(const float* __restrict__ Z, const float* __restrict__ Wz0,
                     const float* __restrict__ WzR, const float* __restrict__ bz,
                     const float* __restrict__ Wu0, float* __restrict__ Pz)
{
  __shared__ float cur[2][64];
  const int hz = blockIdx.x >> 8;
  const int b  = blockIdx.x & 255;
  const int j  = threadIdx.x;
  cur[0][j] = Z[b * 64 + j];
  __syncthreads();
  {
    float acc = bz[hz * 64 + j];
    for (int i = 0; i < 64; ++i) acc += cur[0][i] * Wz0[hz * 4096 + i * 64 + j];
    cur[1][j] = elu(acc);
  }
  __syncthreads();
  for (int m = 1; m < 5; ++m) {
    const int s = m & 1, d = s ^ 1;
    float acc = bz[m * (HZN * 64) + hz * 64 + j];
    const float* W = WzR + ((m - 1) * HZN + hz) * 4096;
    for (int i = 0; i < 64; ++i) acc += cur[s][i] * W[i * 64 + j];
    __syncthreads();
    cur[d][j] = elu(acc);
    __syncthreads();
  }
  for (int t = 0; t < 2; ++t) {
    const int col = j + t * 64;
    float s2 = 0.f;
    for (int i = 0; i < 64; ++i) s2 += cur[1][i] * Wu0[(104 + i) * 128 + col];
    Pz[(hz * BN + b) * 128 + permc(col)] = s2;
  }
}

// ---------------- Xh nets ----------------
__global__ __launch_bounds__(256) void k_xh(const float* __restrict__ X,
                     const float* __restrict__ Wx0, const float* __restrict__ WxR,
                     const float* __restrict__ bx, float* __restrict__ Xh)
{
  __shared__ float WL[4096];
  __shared__ float xin[4][40];
  __shared__ float cur[2][4][64];
  const int hx = blockIdx.x / 1280;
  const int rt = blockIdx.x % 1280;
  const int g = threadIdx.x >> 6;
  const int j = threadIdx.x & 63;
  const int r = rt * 4 + g;
  if (j < 40) xin[g][j] = X[r * 40 + j];
  for (int idx = threadIdx.x; idx < 2560; idx += 256) WL[idx] = Wx0[hx * 2560 + idx];
  __syncthreads();
  {
    float acc = bx[hx * 64 + j];
    for (int i = 0; i < 40; ++i) acc += xin[g][i] * WL[i * 64 + j];
    cur[0][g][j] = elu(acc);
  }
  __syncthreads();
  for (int m = 1; m < 5; ++m) {
    for (int idx = threadIdx.x; idx < 4096; idx += 256)
      WL[idx] = WxR[((m - 1) * HXN + hx) * 4096 + idx];
    __syncthreads();
    float acc = bx[m * (HXN * 64) + hx * 64 + j];
    for (int i = 0; i < 64; ++i) acc += cur[(m - 1) & 1][g][i] * WL[i * 64 + j];
    cur[m & 1][g][j] = elu(acc);
    __syncthreads();
  }
  Xh[hx * 327680 + r * 64 + j] = cur[0][g][j];
}

// ---------------- R = X@Wu0[0:40] + Z@Wu0[168:232] + bu0 (f32, row-major) -----
__global__ __launch_bounds__(256) void k_r(const float* __restrict__ X,
                    const float* __restrict__ Z, const float* __restrict__ Wu0,
                    const float* __restrict__ bu, float* __restrict__ R)
{
  __shared__ float xs[8][40];
  __shared__ float zs[8][64];
  const int r0 = blockIdx.x * 8;
  const int tid = threadIdx.x;
  // 320 elements, 256 threads: MUST grid-stride (round 2-4 bug: `if (tid<320)`
  // left rows 6-7 stale -> deterministic 1.7e-3 absmax failure).
  for (int idx = tid; idx < 320; idx += 256) xs[idx / 40][idx % 40] = X[r0 * 40 + idx];
  for (int idx = tid; idx < 512; idx += 256) {
    const int row = idx >> 6, c = idx & 63;
    zs[row][c] = Z[((r0 + row) / 20) * 64 + c];
  }
  __syncthreads();
  const int row = tid >> 5, cg = tid & 31;
  f32x4 acc = *reinterpret_cast<const f32x4*>(&bu[cg * 4]);
  #pragma unroll 4
  for (int k = 0; k < 40; ++k) {
    const float xv = xs[row][k];
    const f32x4 wv = *reinterpret_cast<const f32x4*>(&Wu0[k * 128 + cg * 4]);
    acc += xv * wv;
  }
  #pragma unroll 4
  for (int k = 0; k < 64; ++k) {
    const float zv = zs[row][k];
    const f32x4 wv = *reinterpret_cast<const f32x4*>(&Wu0[(168 + k) * 128 + cg * 4]);
    acc += zv * wv;
  }
  *reinterpret_cast<f32x4*>(&R[(r0 + row) * 128 + cg * 4]) = acc;
}

// ---------------- Q = R + Xh@Wu0[40:104]  -> f32, perm cols ----------------
__global__ __launch_bounds__(256) void k_q(const float* __restrict__ Xh,
                    const float* __restrict__ R, const float* __restrict__ Wu0,
                    float* __restrict__ Qb)
{
  __shared__ float xh[8][64];
  const int hx = blockIdx.x / 640;
  const int r0 = (blockIdx.x % 640) * 8;
  const int tid = threadIdx.x;
  for (int idx = tid; idx < 512; idx += 256) {
    const int row = idx >> 6, c = idx & 63;
    xh[row][c] = Xh[hx * 327680 + (r0 + row) * 64 + c];
  }
  __syncthreads();
  const int row = tid >> 5, cg = tid & 31;
  f32x4 acc = *reinterpret_cast<const f32x4*>(&R[(r0 + row) * 128 + cg * 4]);
  #pragma unroll 4
  for (int k = 0; k < 64; ++k) {
    const float v = xh[row][k];
    const f32x4 wv = *reinterpret_cast<const f32x4*>(&Wu0[(40 + k) * 128 + cg * 4]);
    acc += v * wv;
  }
  const int pidx = (cg >> 3) * 32 + (cg & 3) * 8 + ((cg >> 2) & 1) * 4;
  *reinterpret_cast<f32x4*>(&Qb[hx * 655360 + (r0 + row) * 128 + pidx]) = acc;
}

// ---------------- fused 4x[128x128] MLP + logits + softmax ----------------
// block 256 = 4 waves. Wave w owns out-cols [32w,32w+32) (m-tiles 2w,2w+1),
// which are exactly k-slice w of the next layer. D-fragments ARE the next
// layer's B-fragments -> register chain + tiny conflict-free b128 exchange.
__global__ __launch_bounds__(256) void k_fused(
    const float* __restrict__ Qb, const float* __restrict__ Pz,
    const float* __restrict__ WuR, const float* __restrict__ bu,
    const float* __restrict__ Wlast, float* __restrict__ partial)
{
  __shared__ __align__(16) unsigned char frag[2][20480]; // [kk][nt][lane][16B]
  __shared__ float lgpS[320];                            // [wave][80 rows]

  const int tid  = threadIdx.x;
  const int w    = tid >> 6;           // wave id = its kk slice
  const int lane = tid & 63;
  const int l16  = lane & 15;
  const int lg   = lane >> 4;
  const int lane16 = lane * 16;

  // ---- per-wave weight A-fragments, all 4 hidden layers (128 VGPRs) ----
  bf16x8 wfrag[4][2][4];
  #pragma unroll
  for (int l = 0; l < 4; ++l)
    #pragma unroll
    for (int mt2 = 0; mt2 < 2; ++mt2)
      #pragma unroll
      for (int kk = 0; kk < 4; ++kk) {
        us8 wv;
        #pragma unroll
        for (int e = 0; e < 8; ++e) {
          const int k = kk * 32 + ((e < 4) ? (4 * lg + e) : (16 + 4 * lg + (e - 4)));
          const int out = (2 * w + mt2) * 16 + l16;
          wv[e] = f2bf(WuR[l * 16384 + k * 128 + out]);
        }
        wfrag[l][mt2][kk] = __builtin_bit_cast(bf16x8, wv);
      }

  // Wlast fragments for this wave's cols
  const f32x4 wl0 = *reinterpret_cast<const f32x4*>(&Wlast[(2 * w) * 16 + 4 * lg]);
  const f32x4 wl1 = *reinterpret_cast<const f32x4*>(&Wlast[(2 * w + 1) * 16 + 4 * lg]);

  // tile-invariant per-lane offsets (float units)
  int qoff[5], pzoff[5];
  #pragma unroll
  for (int nt = 0; nt < 5; ++nt) {
    const int rloc = nt * 16 + l16;
    qoff[nt]  = rloc * 128 + w * 32 + lg * 8;
    pzoff[nt] = (rloc / 20) * 128 + w * 32 + lg * 8;
  }

  for (int tile = blockIdx.x; tile < NTILES; tile += gridDim.x) {
    const int H  = tile >> 6;
    const int tb = tile & 63;
    const int hx = H / HZN, hz = H % HZN;
    const float* qp  = Qb + (size_t)hx * 655360 + tb * (80 * 128);
    const float* pzt = Pz + (hz * BN + tb * 4) * 128;

    // ---- stage u1 = elu(Q + Pz) directly as B-fragments (wave w does kk=w) --
    bf16x8 own[5];
    #pragma unroll
    for (int nt = 0; nt < 5; ++nt) {
      const f32x4 q0  = *reinterpret_cast<const f32x4*>(qp + qoff[nt]);
      const f32x4 q1  = *reinterpret_cast<const f32x4*>(qp + qoff[nt] + 4);
      const f32x4 pz0 = *reinterpret_cast<const f32x4*>(pzt + pzoff[nt]);
      const f32x4 pz1 = *reinterpret_cast<const f32x4*>(pzt + pzoff[nt] + 4);
      us8 o;
      #pragma unroll
      for (int e = 0; e < 4; ++e) o[e] = f2bf(elu(q0[e] + pz0[e]));
      #pragma unroll
      for (int e = 0; e < 4; ++e) o[e + 4] = f2bf(elu(q1[e] + pz1[e]));
      own[nt] = __builtin_bit_cast(bf16x8, o);
      *reinterpret_cast<bf16x8*>(frag[0] + (w * 5 + nt) * 1024 + lane16) = own[nt];
    }
    __syncthreads();

    // ---- 4 hidden layers ----
    #pragma unroll
    for (int l = 0; l < 4; ++l) {
      const unsigned char* rdb = frag[l & 1];
      unsigned char* wrb = frag[(l & 1) ^ 1];
      const f32x4 bia0 = *reinterpret_cast<const f32x4*>(&bu[(l + 1) * 128 + w * 32 + 4 * lg]);
      const f32x4 bia1 = *reinterpret_cast<const f32x4*>(&bu[(l + 1) * 128 + w * 32 + 16 + 4 * lg]);
      #pragma unroll
      for (int nt = 0; nt < 5; ++nt) {
        bf16x8 bfr[4];
        #pragma unroll
        for (int kk = 0; kk < 4; ++kk) {
          bf16x8 ld = *reinterpret_cast<const bf16x8*>(rdb + (kk * 5 + nt) * 1024 + lane16);
          bfr[kk] = (kk == w) ? own[nt] : ld;
        }
        f32x4 a0 = bia0, a1 = bia1;
        #pragma unroll
        for (int kk = 0; kk < 4; ++kk) {
          a0 = __builtin_amdgcn_mfma_f32_16x16x32_bf16(wfrag[l][0][kk], bfr[kk], a0, 0, 0, 0);
          a1 = __builtin_amdgcn_mfma_f32_16x16x32_bf16(wfrag[l][1][kk], bfr[kk], a1, 0, 0, 0);
        }
        if (l < 3) {
          us8 o;
          #pragma unroll
          for (int r = 0; r < 4; ++r) {
            o[r]     = f2bf(elu(a0[r]));
            o[r + 4] = f2bf(elu(a1[r]));
          }
          own[nt] = __builtin_bit_cast(bf16x8, o);
          *reinterpret_cast<bf16x8*>(wrb + (w * 5 + nt) * 1024 + lane16) = own[nt];
        } else {
          float ps = 0.f;
          #pragma unroll
          for (int r = 0; r < 4; ++r)
            ps += elu(a0[r]) * wl0[r] + elu(a1[r]) * wl1[r];
          ps += __shfl_xor(ps, 16);
          ps += __shfl_xor(ps, 32);
          if (lane < 16) lgpS[w * 80 + nt * 16 + l16] = ps;
        }
      }
      __syncthreads();
    }

    // ---- softmax: wave w handles b-group w (20 rows) ----
    {
      const int a = lane;
      const int ar = (a < 20) ? a : 0;
      const int row = w * 20 + ar;
      const float v = lgpS[row] + lgpS[80 + row] + lgpS[160 + row] + lgpS[240 + row];
      float m = (a < 20) ? v : -3.4e38f;
      #pragma unroll
      for (int off = 1; off <= 16; off <<= 1) m = fmaxf(m, __shfl_xor(m, off));
      float e = (a < 20) ? __expf(v - m) : 0.f;
      float s = e;
      #pragma unroll
      for (int off = 1; off <= 16; off <<= 1) s += __shfl_xor(s, off);
      float p = e / s;
      p = (p + 1e-6f) * (1.f / (1.f + 20.f * 1e-6f));
      if (a < 20) partial[(size_t)H * 5120 + tb * 80 + row] = p;
    }
    // frag[0] last read at l=2 (two barriers before next staging); frag[1]
    // last read at l=3 (one barrier). lgpS reads complete before each wave
    // reaches the staging barrier. Safe without an extra barrier here.
  }
}

// ---------------- mean over the 100 (hx,hz) samples ----------------
__global__ void k_reduce(const float* __restrict__ partial, float* __restrict__ out)
{
  const int i = blockIdx.x * 256 + threadIdx.x;
  if (i < 5120) {
    float s = 0.f;
    for (int h = 0; h < 100; ++h) s += partial[(size_t)h * 5120 + i];
    out[i] = s * 0.01f;
  }
}

extern "C" void kernel_launch(void* const* d_in, const int* in_sizes, int n_in,
                              void* d_out, int out_size, void* d_ws, size_t ws_size,
                              hipStream_t stream)
{
  const float* X     = (const float*)d_in[0];
  const float* Z     = (const float*)d_in[1];
  const float* Wx0   = (const float*)d_in[2];
  const float* WxR   = (const float*)d_in[3];
  const float* bx    = (const float*)d_in[4];
  const float* Wz0   = (const float*)d_in[5];
  const float* WzR   = (const float*)d_in[6];
  const float* bz    = (const float*)d_in[7];
  const float* Wu0   = (const float*)d_in[8];
  const float* WuR   = (const float*)d_in[9];
  const float* bu    = (const float*)d_in[10];
  const float* Wlast = (const float*)d_in[11];
  float* out = (float*)d_out;

  float* ws      = (float*)d_ws;
  float* Pz      = ws;                         // 327,680 f32
  float* Xh      = Pz + 327680;                // 3,276,800 f32
  float* Rb      = Xh + 3276800;               // 655,360 f32
  float* Qb      = Rb + 655360;                // 6,553,600 f32
  float* partial = Qb + 6553600;               // 512,000 f32

  hipLaunchKernelGGL(k_zh, dim3(HZN * BN), dim3(64), 0, stream, Z, Wz0, WzR, bz, Wu0, Pz);
  hipLaunchKernelGGL(k_xh, dim3(HXN * 1280), dim3(256), 0, stream, X, Wx0, WxR, bx, Xh);
  hipLaunchKernelGGL(k_r, dim3(640), dim3(256), 0, stream, X, Z, Wu0, bu, Rb);
  hipLaunchKernelGGL(k_q, dim3(HXN * 640), dim3(256), 0, stream, Xh, Rb, Wu0, Qb);
  hipLaunchKernelGGL(k_fused, dim3(512), dim3(256), 0, stream, Qb, Pz, WuR, bu, Wlast, partial);
  hipLaunchKernelGGL(k_reduce, dim3(20), dim3(256), 0, stream, partial, out);
}

// Round 6
// 259.670 us; speedup vs baseline: 2.5831x; 1.5325x over previous
//
#include <hip/hip_runtime.h>
#include <hip/hip_bf16.h>

// Sizes
#define HXN 10
#define HZN 10
#define BN  256
#define AN  20
#define WUN 128
#define NTILES 6400   // (HXN*HZN) * (BN/4)
#define MROWS 80      // 4 b's * 20 a's per tile

typedef float  f32x4  __attribute__((ext_vector_type(4)));
typedef __bf16 bf16x8 __attribute__((ext_vector_type(8)));
typedef unsigned short us8 __attribute__((ext_vector_type(8)));
typedef unsigned u32x2 __attribute__((ext_vector_type(2)));
typedef unsigned u32x4 __attribute__((ext_vector_type(4)));

__device__ __forceinline__ unsigned short f2bf(float f) {
  unsigned u = __builtin_bit_cast(unsigned, f);
  u += 0x7fffu + ((u >> 16) & 1u);   // round-to-nearest-even
  return (unsigned short)(u >> 16);
}
// HW packed f32->bf16 (RNE), 1 instr per 2 values (T12 recipe; no builtin)
__device__ __forceinline__ unsigned cvt_pk(float lo, float hi) {
  unsigned r;
  asm("v_cvt_pk_bf16_f32 %0, %1, %2" : "=v"(r) : "v"(lo), "v"(hi));
  return r;
}
__device__ __forceinline__ float elu(float x) {
  return x > 0.f ? x : (__expf(x) - 1.f);
}
// column permutation so a lane's 8 fragment elements are contiguous:
// col = kk*32 + kappa(lg,e), kappa = (e<4)? 4lg+e : 16+4lg+(e-4)
// perm(col) = kk*32 + lg*8 + e
__device__ __forceinline__ int permc(int c) {
  return (c >> 5) * 32 + ((c >> 2) & 3) * 8 + ((c >> 4) & 1) * 4 + (c & 3);
}

// ------------- weight prep: pack Wx0/WxR + Wu0[40:104] as MFMA A-frags -------
// blocks 0..399: WxP[hx][l][kk][mt][lane][8]  (layer0 K=40 zero-padded to 64)
// blocks 400..415: WuP[kk][mt 0..7][lane][8]
__global__ void k_prep(const float* __restrict__ Wx0, const float* __restrict__ WxR,
                       const float* __restrict__ Wu0,
                       unsigned short* __restrict__ WxP, unsigned short* __restrict__ WuP)
{
  const int b = blockIdx.x;
  const int lane = threadIdx.x;
  const int l16 = lane & 15, lg = lane >> 4;
  us8 o;
  if (b < 400) {
    const int hx = b / 40, rem = b % 40;
    const int l = rem >> 3, rem2 = rem & 7;
    const int kk = rem2 >> 2, mt = rem2 & 3;
    const int m = mt * 16 + l16;
    #pragma unroll
    for (int e = 0; e < 8; ++e) {
      const int k = kk * 32 + ((e < 4) ? (4 * lg + e) : (16 + 4 * lg + (e - 4)));
      float v;
      if (l == 0) v = (k < 40) ? Wx0[hx * 2560 + k * 64 + m] : 0.f;
      else        v = WxR[((l - 1) * 10 + hx) * 4096 + k * 64 + m];
      o[e] = f2bf(v);
    }
    *reinterpret_cast<us8*>(&WxP[(size_t)((((hx * 5 + l) * 2 + kk) * 4 + mt) * 64 + lane) * 8]) = o;
  } else {
    const int i = b - 400;
    const int kk = i >> 3, mt = i & 7;
    #pragma unroll
    for (int e = 0; e < 8; ++e) {
      const int k = kk * 32 + ((e < 4) ? (4 * lg + e) : (16 + 4 * lg + (e - 4)));
      o[e] = f2bf(Wu0[(40 + k) * 128 + mt * 16 + l16]);
    }
    *reinterpret_cast<us8*>(&WuP[((kk * 8 + mt) * 64 + lane) * 8]) = o;
  }
}

// ---------------- zh nets + Pz = zh @ Wu0[104:168] (perm cols) ----------------
__global__ void k_zh(const float* __restrict__ Z, const float* __restrict__ Wz0,
                     const float* __restrict__ WzR, const float* __restrict__ bz,
                     const float* __restrict__ Wu0, float* __restrict__ Pz)
{
  __shared__ float cur[2][64];
  const int hz = blockIdx.x >> 8;
  const int b  = blockIdx.x & 255;
  const int j  = threadIdx.x;
  cur[0][j] = Z[b * 64 + j];
  __syncthreads();
  {
    float acc = bz[hz * 64 + j];
    for (int i = 0; i < 64; ++i) acc += cur[0][i] * Wz0[hz * 4096 + i * 64 + j];
    cur[1][j] = elu(acc);
  }
  __syncthreads();
  for (int m = 1; m < 5; ++m) {
    const int s = m & 1, d = s ^ 1;
    float acc = bz[m * (HZN * 64) + hz * 64 + j];
    const float* W = WzR + ((m - 1) * HZN + hz) * 4096;
    for (int i = 0; i < 64; ++i) acc += cur[s][i] * W[i * 64 + j];
    __syncthreads();
    cur[d][j] = elu(acc);
    __syncthreads();
  }
  for (int t = 0; t < 2; ++t) {
    const int col = j + t * 64;
    float s2 = 0.f;
    for (int i = 0; i < 64; ++i) s2 += cur[1][i] * Wu0[(104 + i) * 128 + col];
    Pz[(hz * BN + b) * 128 + permc(col)] = s2;
  }
}

// ---------------- R = X@Wu0[0:40] + Z@Wu0[168:232] + bu0 (f32, row-major) -----
__global__ __launch_bounds__(256) void k_r(const float* __restrict__ X,
                    const float* __restrict__ Z, const float* __restrict__ Wu0,
                    const float* __restrict__ bu, float* __restrict__ R)
{
  __shared__ float xs[8][40];
  __shared__ float zs[8][64];
  const int r0 = blockIdx.x * 8;
  const int tid = threadIdx.x;
  for (int idx = tid; idx < 320; idx += 256) xs[idx / 40][idx % 40] = X[r0 * 40 + idx];
  for (int idx = tid; idx < 512; idx += 256) {
    const int row = idx >> 6, c = idx & 63;
    zs[row][c] = Z[((r0 + row) / 20) * 64 + c];
  }
  __syncthreads();
  const int row = tid >> 5, cg = tid & 31;
  f32x4 acc = *reinterpret_cast<const f32x4*>(&bu[cg * 4]);
  #pragma unroll 4
  for (int k = 0; k < 40; ++k) {
    const float xv = xs[row][k];
    const f32x4 wv = *reinterpret_cast<const f32x4*>(&Wu0[k * 128 + cg * 4]);
    acc += xv * wv;
  }
  #pragma unroll 4
  for (int k = 0; k < 64; ++k) {
    const float zv = zs[row][k];
    const f32x4 wv = *reinterpret_cast<const f32x4*>(&Wu0[(168 + k) * 128 + cg * 4]);
    acc += zv * wv;
  }
  *reinterpret_cast<f32x4*>(&R[(r0 + row) * 128 + cg * 4]) = acc;
}

// -------- eps(X) nets via MFMA, fused with Q = R + Xh@Wu0[40:104] ------------
// block = 4 waves, 80 rows, one hx. Wave w owns out-cols 16w..16w+16; its
// D-frag is half of next layer's B-frag (kk=w>>1): b64 write + b128 read.
// Final layer (N=128): wave w owns cols 32w..32w+32, writes Q f32 (perm cols).
__global__ __launch_bounds__(256) void k_xq(
    const float* __restrict__ X, const float* __restrict__ bx,
    const float* __restrict__ R,
    const unsigned short* __restrict__ WxP, const unsigned short* __restrict__ WuP,
    float* __restrict__ Qb)
{
  __shared__ __align__(16) unsigned char bufA[10240];  // [kk 2][nt 5][lane 64][16B]
  __shared__ __align__(16) unsigned char bufB[10240];
  const int hx = blockIdx.x >> 6;
  const int rt = blockIdx.x & 63;
  const int r0 = rt * 80;
  const int tid = threadIdx.x;
  const int w = tid >> 6, lane = tid & 63;
  const int l16 = lane & 15, lg = lane >> 4;
  const int lane16 = lane * 16;

  // A-frags (coalesced b128 from prepped arrays)
  bf16x8 WA[5][2];
  #pragma unroll
  for (int l = 0; l < 5; ++l)
    #pragma unroll
    for (int kk = 0; kk < 2; ++kk)
      WA[l][kk] = *reinterpret_cast<const bf16x8*>(
          &WxP[(size_t)((((hx * 5 + l) * 2 + kk) * 4 + w) * 64 + lane) * 8]);
  bf16x8 WQ[2][2];
  #pragma unroll
  for (int kk = 0; kk < 2; ++kk)
    #pragma unroll
    for (int mt2 = 0; mt2 < 2; ++mt2)
      WQ[kk][mt2] = *reinterpret_cast<const bf16x8*>(
          &WuP[((kk * 8 + 2 * w + mt2) * 64 + lane) * 8]);

  // stage X -> bufA as layer-1 B-frags (K padded 40->64 with zeros)
  for (int idx = tid; idx < 5120; idx += 256) {
    const int row = idx >> 6, k = idx & 63;
    const float v = (k < 40) ? X[(r0 + row) * 40 + k] : 0.f;
    const int kk = k >> 5, kl = k & 31;
    const int flg = (kl & 15) >> 2, fe = (kl & 3) + 4 * (kl >> 4);
    const int fl = (row & 15) + 16 * flg, nt = row >> 4;
    *reinterpret_cast<unsigned short*>(bufA + ((kk * 5 + nt) * 64 + fl) * 16 + fe * 2) = f2bf(v);
  }
  __syncthreads();

  const int kkp = w >> 1, half = w & 1;
  #pragma unroll
  for (int l = 0; l < 5; ++l) {
    const unsigned char* src = (l & 1) ? bufB : bufA;
    unsigned char* dst = (l & 1) ? bufA : bufB;
    const f32x4 bias = *reinterpret_cast<const f32x4*>(&bx[(l * 10 + hx) * 64 + w * 16 + 4 * lg]);
    #pragma unroll
    for (int nt = 0; nt < 5; ++nt) {
      const bf16x8 B0 = *reinterpret_cast<const bf16x8*>(src + nt * 1024 + lane16);
      const bf16x8 B1 = *reinterpret_cast<const bf16x8*>(src + (5 + nt) * 1024 + lane16);
      f32x4 acc = bias;
      acc = __builtin_amdgcn_mfma_f32_16x16x32_bf16(WA[l][0], B0, acc, 0, 0, 0);
      acc = __builtin_amdgcn_mfma_f32_16x16x32_bf16(WA[l][1], B1, acc, 0, 0, 0);
      u32x2 o;
      o[0] = cvt_pk(elu(acc[0]), elu(acc[1]));
      o[1] = cvt_pk(elu(acc[2]), elu(acc[3]));
      *reinterpret_cast<u32x2*>(dst + (kkp * 5 + nt) * 1024 + lane16 + half * 8) = o;
    }
    __syncthreads();
  }

  // Q layer: N=128, input = layer-5 frags in bufB; C-init = R (includes bu0)
  #pragma unroll
  for (int nt = 0; nt < 5; ++nt) {
    const bf16x8 B0 = *reinterpret_cast<const bf16x8*>(bufB + nt * 1024 + lane16);
    const bf16x8 B1 = *reinterpret_cast<const bf16x8*>(bufB + (5 + nt) * 1024 + lane16);
    const int grow = r0 + nt * 16 + l16;
    #pragma unroll
    for (int mt2 = 0; mt2 < 2; ++mt2) {
      f32x4 acc = *reinterpret_cast<const f32x4*>(&R[grow * 128 + (2 * w + mt2) * 16 + 4 * lg]);
      acc = __builtin_amdgcn_mfma_f32_16x16x32_bf16(WQ[0][mt2], B0, acc, 0, 0, 0);
      acc = __builtin_amdgcn_mfma_f32_16x16x32_bf16(WQ[1][mt2], B1, acc, 0, 0, 0);
      *reinterpret_cast<f32x4*>(&Qb[(size_t)hx * 655360 + grow * 128 + w * 32 + lg * 8 + 4 * mt2]) = acc;
    }
  }
}

// ---------------- fused 4x[128x128] MLP + logits + softmax ----------------
// block 256 = 4 waves. Wave w owns out-cols [32w,32w+32) (m-tiles 2w,2w+1),
// which are exactly k-slice w of the next layer. D-fragments ARE the next
// layer's B-fragments -> register chain + tiny conflict-free b128 exchange.
__global__ __launch_bounds__(256) void k_fused(
    const float* __restrict__ Qb, const float* __restrict__ Pz,
    const float* __restrict__ WuR, const float* __restrict__ bu,
    const float* __restrict__ Wlast, float* __restrict__ partial)
{
  __shared__ __align__(16) unsigned char frag[2][20480]; // [kk][nt][lane][16B]
  __shared__ float lgpS[320];                            // [wave][80 rows]

  const int tid  = threadIdx.x;
  const int w    = tid >> 6;           // wave id = its kk slice
  const int lane = tid & 63;
  const int l16  = lane & 15;
  const int lg   = lane >> 4;
  const int lane16 = lane * 16;

  // ---- per-wave weight A-fragments, all 4 hidden layers (128 VGPRs) ----
  bf16x8 wfrag[4][2][4];
  #pragma unroll
  for (int l = 0; l < 4; ++l)
    #pragma unroll
    for (int mt2 = 0; mt2 < 2; ++mt2)
      #pragma unroll
      for (int kk = 0; kk < 4; ++kk) {
        us8 wv;
        #pragma unroll
        for (int e = 0; e < 8; ++e) {
          const int k = kk * 32 + ((e < 4) ? (4 * lg + e) : (16 + 4 * lg + (e - 4)));
          const int out = (2 * w + mt2) * 16 + l16;
          wv[e] = f2bf(WuR[l * 16384 + k * 128 + out]);
        }
        wfrag[l][mt2][kk] = __builtin_bit_cast(bf16x8, wv);
      }

  // Wlast fragments for this wave's cols
  const f32x4 wl0 = *reinterpret_cast<const f32x4*>(&Wlast[(2 * w) * 16 + 4 * lg]);
  const f32x4 wl1 = *reinterpret_cast<const f32x4*>(&Wlast[(2 * w + 1) * 16 + 4 * lg]);

  // tile-invariant per-lane offsets (float units)
  int qoff[5], pzoff[5];
  #pragma unroll
  for (int nt = 0; nt < 5; ++nt) {
    const int rloc = nt * 16 + l16;
    qoff[nt]  = rloc * 128 + w * 32 + lg * 8;
    pzoff[nt] = (rloc / 20) * 128 + w * 32 + lg * 8;
  }

  for (int tile = blockIdx.x; tile < NTILES; tile += gridDim.x) {
    const int H  = tile >> 6;
    const int tb = tile & 63;
    const int hx = H / HZN, hz = H % HZN;
    const float* qp  = Qb + (size_t)hx * 655360 + tb * (80 * 128);
    const float* pzt = Pz + (hz * BN + tb * 4) * 128;

    // ---- stage u1 = elu(Q + Pz) directly as B-fragments (wave w does kk=w) --
    bf16x8 own[5];
    #pragma unroll
    for (int nt = 0; nt < 5; ++nt) {
      const f32x4 q0  = *reinterpret_cast<const f32x4*>(qp + qoff[nt]);
      const f32x4 q1  = *reinterpret_cast<const f32x4*>(qp + qoff[nt] + 4);
      const f32x4 pz0 = *reinterpret_cast<const f32x4*>(pzt + pzoff[nt]);
      const f32x4 pz1 = *reinterpret_cast<const f32x4*>(pzt + pzoff[nt] + 4);
      u32x4 o;
      o[0] = cvt_pk(elu(q0[0] + pz0[0]), elu(q0[1] + pz0[1]));
      o[1] = cvt_pk(elu(q0[2] + pz0[2]), elu(q0[3] + pz0[3]));
      o[2] = cvt_pk(elu(q1[0] + pz1[0]), elu(q1[1] + pz1[1]));
      o[3] = cvt_pk(elu(q1[2] + pz1[2]), elu(q1[3] + pz1[3]));
      own[nt] = __builtin_bit_cast(bf16x8, o);
      *reinterpret_cast<bf16x8*>(frag[0] + (w * 5 + nt) * 1024 + lane16) = own[nt];
    }
    __syncthreads();

    // ---- 4 hidden layers ----
    #pragma unroll
    for (int l = 0; l < 4; ++l) {
      const unsigned char* rdb = frag[l & 1];
      unsigned char* wrb = frag[(l & 1) ^ 1];
      const f32x4 bia0 = *reinterpret_cast<const f32x4*>(&bu[(l + 1) * 128 + w * 32 + 4 * lg]);
      const f32x4 bia1 = *reinterpret_cast<const f32x4*>(&bu[(l + 1) * 128 + w * 32 + 16 + 4 * lg]);
      #pragma unroll
      for (int nt = 0; nt < 5; ++nt) {
        bf16x8 bfr[4];
        #pragma unroll
        for (int kk = 0; kk < 4; ++kk) {
          bf16x8 ld = *reinterpret_cast<const bf16x8*>(rdb + (kk * 5 + nt) * 1024 + lane16);
          bfr[kk] = (kk == w) ? own[nt] : ld;
        }
        f32x4 a0 = bia0, a1 = bia1;
        #pragma unroll
        for (int kk = 0; kk < 4; ++kk) {
          a0 = __builtin_amdgcn_mfma_f32_16x16x32_bf16(wfrag[l][0][kk], bfr[kk], a0, 0, 0, 0);
          a1 = __builtin_amdgcn_mfma_f32_16x16x32_bf16(wfrag[l][1][kk], bfr[kk], a1, 0, 0, 0);
        }
        if (l < 3) {
          u32x4 o;
          o[0] = cvt_pk(elu(a0[0]), elu(a0[1]));
          o[1] = cvt_pk(elu(a0[2]), elu(a0[3]));
          o[2] = cvt_pk(elu(a1[0]), elu(a1[1]));
          o[3] = cvt_pk(elu(a1[2]), elu(a1[3]));
          own[nt] = __builtin_bit_cast(bf16x8, o);
          *reinterpret_cast<bf16x8*>(wrb + (w * 5 + nt) * 1024 + lane16) = own[nt];
        } else {
          float ps = 0.f;
          #pragma unroll
          for (int r = 0; r < 4; ++r)
            ps += elu(a0[r]) * wl0[r] + elu(a1[r]) * wl1[r];
          ps += __shfl_xor(ps, 16);
          ps += __shfl_xor(ps, 32);
          if (lane < 16) lgpS[w * 80 + nt * 16 + l16] = ps;
        }
      }
      __syncthreads();
    }

    // ---- softmax: wave w handles b-group w (20 rows) ----
    {
      const int a = lane;
      const int ar = (a < 20) ? a : 0;
      const int row = w * 20 + ar;
      const float v = lgpS[row] + lgpS[80 + row] + lgpS[160 + row] + lgpS[240 + row];
      float m = (a < 20) ? v : -3.4e38f;
      #pragma unroll
      for (int off = 1; off <= 16; off <<= 1) m = fmaxf(m, __shfl_xor(m, off));
      float e = (a < 20) ? __expf(v - m) : 0.f;
      float s = e;
      #pragma unroll
      for (int off = 1; off <= 16; off <<= 1) s += __shfl_xor(s, off);
      float p = e / s;
      p = (p + 1e-6f) * (1.f / (1.f + 20.f * 1e-6f));
      if (a < 20) partial[(size_t)H * 5120 + tb * 80 + row] = p;
    }
    // frag[0] last read at l=2 (two barriers before next staging); frag[1]
    // last read at l=3 (one barrier). lgpS reads complete before each wave
    // reaches the staging barrier. Safe without an extra barrier here.
  }
}

// ---------------- mean over the 100 (hx,hz) samples ----------------
__global__ void k_reduce(const float* __restrict__ partial, float* __restrict__ out)
{
  const int i = blockIdx.x * 256 + threadIdx.x;
  if (i < 5120) {
    float s = 0.f;
    for (int h = 0; h < 100; ++h) s += partial[(size_t)h * 5120 + i];
    out[i] = s * 0.01f;
  }
}

extern "C" void kernel_launch(void* const* d_in, const int* in_sizes, int n_in,
                              void* d_out, int out_size, void* d_ws, size_t ws_size,
                              hipStream_t stream)
{
  const float* X     = (const float*)d_in[0];
  const float* Z     = (const float*)d_in[1];
  const float* Wx0   = (const float*)d_in[2];
  const float* WxR   = (const float*)d_in[3];
  const float* bx    = (const float*)d_in[4];
  const float* Wz0   = (const float*)d_in[5];
  const float* WzR   = (const float*)d_in[6];
  const float* bz    = (const float*)d_in[7];
  const float* Wu0   = (const float*)d_in[8];
  const float* WuR   = (const float*)d_in[9];
  const float* bu    = (const float*)d_in[10];
  const float* Wlast = (const float*)d_in[11];
  float* out = (float*)d_out;

  float* ws      = (float*)d_ws;
  float* Pz      = ws;                          // 327,680 f32
  float* Rb      = Pz + 327680;                 // 655,360 f32
  float* Qb      = Rb + 655360;                 // 6,553,600 f32
  float* partial = Qb + 6553600;                // 512,000 f32
  unsigned short* WxP = (unsigned short*)(partial + 512000);  // 204,800 us
  unsigned short* WuP = WxP + 204800;           // 8,192 us

  hipLaunchKernelGGL(k_prep, dim3(416), dim3(64), 0, stream, Wx0, WxR, Wu0, WxP, WuP);
  hipLaunchKernelGGL(k_zh, dim3(HZN * BN), dim3(64), 0, stream, Z, Wz0, WzR, bz, Wu0, Pz);
  hipLaunchKernelGGL(k_r, dim3(640), dim3(256), 0, stream, X, Z, Wu0, bu, Rb);
  hipLaunchKernelGGL(k_xq, dim3(640), dim3(256), 0, stream, X, bx, Rb, WxP, WuP, Qb);
  hipLaunchKernelGGL(k_fused, dim3(640), dim3(256), 0, stream, Qb, Pz, WuR, bu, Wlast, partial);
  hipLaunchKernelGGL(k_reduce, dim3(20), dim3(256), 0, stream, partial, out);
}